// Round 7
// baseline (124.902 us; speedup 1.0000x reference)
//
#include <hip/hip_runtime.h>
#include <math.h>

#define LOG2E 1.4426950408889634f
#define LN2F  0.6931471805599453f
#define NEGB  (-1e30f)

__device__ __forceinline__ float fexp2(float x){ float r; asm("v_exp_f32 %0, %1":"=v"(r):"v"(x)); return r; }
__device__ __forceinline__ float flog2(float x){ float r; asm("v_log_f32 %0, %1":"=v"(r):"v"(x)); return r; }

// DPP helper: invalid source lanes produce 0 (old=0, bound_ctrl off).
template<int CTRL>
__device__ __forceinline__ float dppf(float x){
    return __int_as_float(__builtin_amdgcn_update_dpp(0, __float_as_int(x), CTRL, 0xf, 0xf, false));
}

// LDS gather read, opaque to the compiler (no compiler-inserted vmcnt(0)
// against outstanding global_load_lds). Ordering done by explicit counted
// waits + sched_barrier(0) per rule #18.
__device__ __forceinline__ float ldsread(unsigned addr){
    float r;
    asm volatile("ds_read_b32 %0, %1" : "=v"(r) : "v"(addr));
    return r;
}

#define WAITV(N) asm volatile("s_waitcnt vmcnt(" #N ")" ::: "memory")
#define WAITL(N) asm volatile("s_waitcnt lgkmcnt(" #N ")" ::: "memory")
#define SB0() __builtin_amdgcn_sched_barrier(0)

// One wave per (sample, sequence). Lane owns extended positions 4l..4l+3.
// Alpha in LINEAR probability domain, wave-uniform scale 2^E (exact),
// rescaled every 6 steps via DPP wave-max; invalid positions emit-masked to
// exactly 0. Neighbor alpha[4l-1] via DPP row_shr:1 + row_bcast15.
// Class rows stream HBM -> LDS ring (32 x 1KB) via ONE coalesced
// global_load_lds per row (24 rows in flight, vmcnt(22) per step); emits
// gathered from LDS 2 steps ahead via asm ds_read + lgkmcnt(6).
__global__ __launch_bounds__(64) void ctc_scan_kernel(
    const float* __restrict__ lp,        // (T, N, C) log-probs
    const int* __restrict__ labels,      // (N, S)
    const int* __restrict__ rlabels,     // (N, S)
    const int* __restrict__ ilen,        // (N,)
    const int* __restrict__ llen,        // (N,)
    const int* __restrict__ rlen,        // (N,)
    float* __restrict__ loss,            // (2N,)
    int T, int N, int C, int S)
{
    const int n    = blockIdx.x >> 1;
    const int sq   = blockIdx.x & 1;
    const int lane = threadIdx.x;

    const int* lab = sq ? rlabels : labels;
    const int  ll  = sq ? rlen[n] : llen[n];
    int Teff = ilen[n]; if (Teff > T) Teff = T;
    const int Tm1 = T - 1;

    __shared__ __align__(16) float ring[32][256];   // 32KB row ring
    __shared__ __align__(16) float aout[256];

    // labels for odd positions s=4l+1 (j0=2l), s=4l+3 (j1=2l+1)
    int e1 = 0, e3 = 0;
    bool k1 = false, k3 = false;
    {
        int j0 = 2*lane, j1 = 2*lane + 1;
        if (j0 < S){ e1 = lab[n*S + j0]; if (j0 > 0) k1 = (e1 != lab[n*S + j0 - 1]); }
        if (j1 < S){ e3 = lab[n*S + j1]; k3 = (e3 != e1); }
    }
    // validity: position s is real iff s <= 2*ll
    const float m0 = (2*lane     <= ll) ? 1.f : 0.f;   // s=4l   (blank)
    const float m2 = (2*lane + 1 <= ll) ? 1.f : 0.f;   // s=4l+2 (blank)
    const float b1 = (2*lane     <  ll) ? 0.f : NEGB;  // s=4l+1
    const float b3 = (2*lane + 1 <  ll) ? 0.f : NEGB;  // s=4l+3
    const bool bnd = ((lane & 15) == 0) && (lane != 0);  // lanes 16,32,48

    const size_t NC = (size_t)N * C;
    const float* base = lp + (size_t)n * C;
    const float* gsrc = base + lane * 4;               // per-lane 16B slot

    // LDS byte addresses for the three gathers (slot offset added per step)
    const unsigned RB = (unsigned)(size_t)(__attribute__((address_space(3))) char*)&ring[0][0];
    const unsigned ab = RB;                            // class 0 (uniform -> broadcast)
    const unsigned ax = RB + 4u * (unsigned)e1;
    const unsigned ay = RB + 4u * (unsigned)e3;

    // t=0 init from direct global loads (compiler-managed, drained below)
    float a0, a1, a2 = 0.f, a3 = 0.f;
    {
        float pb0 = fexp2(base[0]  * LOG2E);
        float p10 = fexp2(base[e1] * LOG2E);
        a0 = (lane == 0) ? pb0 : 0.f;
        a1 = (lane == 0) ? p10 : 0.f;
    }
    int E = 0;   // true alpha = a * 2^E

    asm volatile("s_waitcnt vmcnt(0) lgkmcnt(0)" ::: "memory");
    SB0();

    auto stage = [&](int row){                         // one 1KB row -> ring
        int rr = row < Tm1 ? row : Tm1;                // slot keyed by UNclamped row
        __builtin_amdgcn_global_load_lds(
            (const __attribute__((address_space(1))) char*)(gsrc + (size_t)rr * NC),
            (__attribute__((address_space(3))) char*)&ring[row & 31][0],
            16, 0, 0);
    };

    float emB[3], emX[3], emY[3];
    auto issue_reads = [&](int row, int p){
        unsigned so = (unsigned)((row & 31) << 10);
        emB[p] = ldsread(ab + so);
        emX[p] = ldsread(ax + so);
        emY[p] = ldsread(ay + so);
    };

    auto stepf = [&](int P){
        float pb = fexp2(emB[P] * LOG2E);
        float p1 = fexp2(fmaf(emX[P], LOG2E, b1));     // invalid -> exp2(-1e30) = 0
        float p3 = fexp2(fmaf(emY[P], LOG2E, b3));
        float sh = dppf<0x111>(a3);                    // row_shr:1 (lanes 0/16/32/48 -> 0)
        float bc = dppf<0x142>(a3);                    // row_bcast15
        float pa3 = bnd ? bc : sh;                     // prev-lane a3; lane0 -> 0
        float v0 = (a0 + pa3) * (pb * m0);
        float v1 = (a1 + a0 + (k1 ? pa3 : 0.f)) * p1;
        float v2 = (a2 + a1) * (pb * m2);
        float v3 = (a3 + a2 + (k3 ? a1 : 0.f)) * p3;
        a0 = v0; a1 = v1; a2 = v2; a3 = v3;
    };

    // full step: stage row t+24; ensure row t+2 resident; prefetch its emits;
    // consume row t's emits (issued 2 steps ago) behind lgkmcnt(6)+SB0.
    auto STEPQ = [&](int tcur, int P, int Pn){
        stage(tcur + 24);
        WAITV(22);                                     // rows <= tcur+2 staged
        issue_reads(tcur + 2, Pn);
        WAITL(6);                                      // row tcur's 3 reads done
        SB0();                                         // nothing hoists above the wait
        stepf(P);
    };

    auto rescale = [&](){
        float m = fmaxf(fmaxf(a0, a1), fmaxf(a2, a3));
        m = fmaxf(m, dppf<0x111>(m));
        m = fmaxf(m, dppf<0x112>(m));
        m = fmaxf(m, dppf<0x114>(m));
        m = fmaxf(m, dppf<0x118>(m));
        m = fmaxf(m, dppf<0x142>(m));
        m = fmaxf(m, dppf<0x143>(m));                  // lane63 = wave max
        float wmax = __int_as_float(__builtin_amdgcn_readlane(__float_as_int(m), 63));
        int ex = ((__float_as_int(wmax) >> 23) & 255) - 127;
        a0 = ldexpf(a0, -ex); a1 = ldexpf(a1, -ex);
        a2 = ldexpf(a2, -ex); a3 = ldexpf(a3, -ex);
        E += ex;
    };

    // prologue: rows 1..24 in flight; rows 1,2 emits prefetched
#pragma unroll
    for (int r = 1; r <= 24; ++r) stage(r);
    WAITV(22);                                         // rows 1,2 staged
    issue_reads(1, 1);
    issue_reads(2, 2);

    int t = 1;
    for (; t + 6 <= Teff; t += 6){                     // t === 1 (mod 3) throughout
        STEPQ(t + 0, 1, 0);
        STEPQ(t + 1, 2, 1);
        STEPQ(t + 2, 0, 2);
        STEPQ(t + 3, 1, 0);
        STEPQ(t + 4, 2, 1);
        STEPQ(t + 5, 0, 2);
        rescale();
    }
    {   // tail (<6 steps), same static phase pattern
        if (t + 0 < Teff) STEPQ(t + 0, 1, 0);
        if (t + 1 < Teff) STEPQ(t + 1, 2, 1);
        if (t + 2 < Teff) STEPQ(t + 2, 0, 2);
        if (t + 3 < Teff) STEPQ(t + 3, 1, 0);
        if (t + 4 < Teff) STEPQ(t + 4, 2, 1);
    }

    asm volatile("s_waitcnt vmcnt(0) lgkmcnt(0)" ::: "memory");
    SB0();

    reinterpret_cast<float4*>(aout)[lane] = make_float4(a0, a1, a2, a3);
    __syncthreads();
    if (lane == 0){
        float hi = aout[2*ll], lo = aout[2*ll - 1];
        loss[sq * N + n] = -(flog2(hi + lo) + (float)E) * LN2F;
    }
}

__global__ __launch_bounds__(256) void ctc_finalize_kernel(
    const float* __restrict__ ws, float* __restrict__ out, int N)
{
    __shared__ float sc[256], sh[256];
    const int i = threadIdx.x;
    float c = 0.f, h = 0.f;
    for (int nn = i; nn < N; nn += 256) {
        float cv = ws[nn];
        float rv = ws[N + nn];
        c += cv;
        float dap = fabsf(1e-6f - cv);
        float dan = fabsf(1e-6f - rv);
        h += fmaxf(dap - dan + 16.0f, 0.f);
    }
    sc[i] = c; sh[i] = h;
    __syncthreads();
    for (int off = 128; off > 0; off >>= 1) {
        if (i < off) { sc[i] += sc[i + off]; sh[i] += sh[i + off]; }
        __syncthreads();
    }
    if (i == 0) out[0] = sc[0] + sh[0] / (float)N;
}

extern "C" void kernel_launch(void* const* d_in, const int* in_sizes, int n_in,
                              void* d_out, int out_size, void* d_ws, size_t ws_size,
                              hipStream_t stream) {
    const float* lp      = (const float*)d_in[0];   // predicts (T,N,C) f32
    const int* labels    = (const int*)d_in[1];     // (N,S)
    const int* rlabels   = (const int*)d_in[2];     // (N,S)
    const int* plen      = (const int*)d_in[3];     // (N,)
    const int* llen      = (const int*)d_in[4];     // (N,)
    const int* rlen      = (const int*)d_in[5];     // (N,)

    const int N = in_sizes[3];
    const int S = in_sizes[1] / N;
    const int C = 256;
    const int T = in_sizes[0] / (N * C);

    float* ws = (float*)d_ws;                       // 2N floats of per-seq losses

    ctc_scan_kernel<<<2 * N, 64, 0, stream>>>(lp, labels, rlabels, plen, llen, rlen,
                                              ws, T, N, C, S);
    ctc_finalize_kernel<<<1, 256, 0, stream>>>(ws, (float*)d_out, N);
}

// Round 14
// 109.694 us; speedup vs baseline: 1.1386x; 1.1386x over previous
//
#include <hip/hip_runtime.h>
#include <math.h>

#define LOG2E 1.4426950408889634f
#define LN2F  0.6931471805599453f
#define NEGB  (-1e30f)

__device__ __forceinline__ float fexp2(float x){ float r; asm("v_exp_f32 %0, %1":"=v"(r):"v"(x)); return r; }
__device__ __forceinline__ float flog2(float x){ float r; asm("v_log_f32 %0, %1":"=v"(r):"v"(x)); return r; }

// DPP helper: invalid source lanes produce 0 (old=0, bound_ctrl off).
template<int CTRL>
__device__ __forceinline__ float dppf(float x){
    return __int_as_float(__builtin_amdgcn_update_dpp(0, __float_as_int(x), CTRL, 0xf, 0xf, false));
}

// Pinned gather load, flat 64-bit VGPR address (assembles regardless of
// uniformity). asm volatile can't be sunk; outputs are NAMED SCALARS this
// round (R13 post-mortem: array pipelines were lowered to scratch — VGPR=44
// < 54 live values — adding hidden VMEM ops that corrupted counted-vmcnt
// accounting and put L2 latency in every step).
__device__ __forceinline__ float gload(const float* p){
    float r;
    asm volatile("global_load_dword %0, %1, off" : "=v"(r) : "v"(p));
    return r;
}
#define WAITV(N) asm volatile("s_waitcnt vmcnt(" #N ")" ::: "memory")
#define SB0() __builtin_amdgcn_sched_barrier(0)

#define RESCALE4(x0,x1,x2,x3,E)                                              \
    {                                                                        \
        float mx_ = fmaxf(fmaxf(x0,x1), fmaxf(x2,x3));                       \
        mx_ = fmaxf(mx_, dppf<0x111>(mx_));                                  \
        mx_ = fmaxf(mx_, dppf<0x112>(mx_));                                  \
        mx_ = fmaxf(mx_, dppf<0x114>(mx_));                                  \
        mx_ = fmaxf(mx_, dppf<0x118>(mx_));                                  \
        mx_ = fmaxf(mx_, dppf<0x142>(mx_));                                  \
        mx_ = fmaxf(mx_, dppf<0x143>(mx_));                                  \
        float wm_ = __int_as_float(__builtin_amdgcn_readlane(__float_as_int(mx_), 63)); \
        int ex_ = ((__float_as_int(wm_) >> 23) & 255) - 127;                 \
        x0 = ldexpf(x0,-ex_); x1 = ldexpf(x1,-ex_);                          \
        x2 = ldexpf(x2,-ex_); x3 = ldexpf(x3,-ex_);                          \
        E += ex_;                                                            \
    }

// One wave per (sample, sequence); lane owns extended positions 4l..4l+3.
// Linear-domain alpha with exact 2^E rescale every 6 steps; invalid
// positions emit-masked to exact 0; neighbor alpha[4l-1] via DPP row_shr:1
// + row_bcast15. Emits stream through a 12-row NAMED-REGISTER pipeline
// (36 floats, 4 banks x 3 rows), counted WAITV(27) per 3-step group.
__global__ __launch_bounds__(64) void ctc_scan_kernel(
    const float* __restrict__ lp,        // (T, N, C) log-probs
    const int* __restrict__ labels,      // (N, S)
    const int* __restrict__ rlabels,     // (N, S)
    const int* __restrict__ ilen,        // (N,)
    const int* __restrict__ llen,        // (N,)
    const int* __restrict__ rlen,        // (N,)
    float* __restrict__ loss,            // (2N,)
    int T, int N, int C, int S)
{
    const int n    = blockIdx.x >> 1;
    const int sq   = blockIdx.x & 1;
    const int lane = threadIdx.x;

    const int* lab = sq ? rlabels : labels;
    const int  ll  = sq ? rlen[n] : llen[n];
    int Teff = ilen[n]; if (Teff > T) Teff = T; if (Teff < 1) Teff = 1;
    const int Tm1 = T - 1;

    const int j0 = 2*lane, j1 = 2*lane + 1;
    int e1 = 0, e3 = 0; bool k1 = false, k3 = false;
    if (j0 < S){ e1 = lab[n*S + j0]; if (j0 > 0) k1 = (e1 != lab[n*S + j0 - 1]); }
    if (j1 < S){ e3 = lab[n*S + j1]; k3 = (e3 != e1); }
    const float m0 = (j0 <= ll) ? 1.f : 0.f;   // even position 4l
    const float m2 = (j1 <= ll) ? 1.f : 0.f;   // even position 4l+2
    const float b1 = (j0 <  ll) ? 0.f : NEGB;  // odd 4l+1
    const float b3 = (j1 <  ll) ? 0.f : NEGB;  // odd 4l+3
    const bool bnd = ((lane & 15) == 0) && (lane != 0);  // lanes 16,32,48

    const size_t NC = (size_t)N * C;
    const float* base = lp + (size_t)n * C;

    float a0, a1, a2 = 0.f, a3 = 0.f;
    {
        float pb0 = fexp2(base[0]  * LOG2E);
        float p10 = fexp2(base[e1] * LOG2E);
        a0 = (lane == 0) ? pb0 : 0.f;
        a1 = (lane == 0) ? p10 : 0.f;
    }
    int E = 0;                                 // true alpha = a * 2^E

    // pin loop-invariant scalars; drain init loads before the pipeline
    asm volatile("" :: "v"(m0), "v"(m2), "v"(b1), "v"(b3), "v"(e1), "v"(e3));
    asm volatile("s_waitcnt vmcnt(0) lgkmcnt(0)" ::: "memory"); SB0();

#define LOAD3(Ba,Xa,Ya,row_) {                                    \
        int r_ = (row_); if (r_ > Tm1) r_ = Tm1;                  \
        const float* rp_ = base + (size_t)r_ * NC;                \
        Ba = gload(rp_); Xa = gload(rp_ + e1); Ya = gload(rp_ + e3); }

    auto stepf = [&](float PB, float PX, float PY){
        float pb = fexp2(PB * LOG2E);
        float p1 = fexp2(fmaf(PX, LOG2E, b1));   // invalid -> 0
        float p3 = fexp2(fmaf(PY, LOG2E, b3));
        float sh = dppf<0x111>(a3);              // prev lane's a3
        float bc = dppf<0x142>(a3);
        float pa3 = bnd ? bc : sh;
        float v0 = (a0 + pa3) * (pb * m0);
        float v1 = (a1 + a0 + (k1 ? pa3 : 0.f)) * p1;
        float v2 = (a2 + a1) * (pb * m2);
        float v3 = (a3 + a2 + (k3 ? a1 : 0.f)) * p3;
        a0 = v0; a1 = v1; a2 = v2; a3 = v3;
    };

    // 36 NAMED pipeline registers: bank q row u holds emits for row t+3q+u
    float B0a,X0a,Y0a, B0b,X0b,Y0b, B0c,X0c,Y0c;
    float B1a,X1a,Y1a, B1b,X1b,Y1b, B1c,X1c,Y1c;
    float B2a,X2a,Y2a, B2b,X2b,Y2b, B2c,X2c,Y2c;
    float B3a,X3a,Y3a, B3b,X3b,Y3b, B3c,X3c,Y3c;

    // prologue: rows 1..12 in flight (36 loads)
    LOAD3(B0a,X0a,Y0a, 1);  LOAD3(B0b,X0b,Y0b, 2);  LOAD3(B0c,X0c,Y0c, 3);
    LOAD3(B1a,X1a,Y1a, 4);  LOAD3(B1b,X1b,Y1b, 5);  LOAD3(B1c,X1c,Y1c, 6);
    LOAD3(B2a,X2a,Y2a, 7);  LOAD3(B2b,X2b,Y2b, 8);  LOAD3(B2c,X2c,Y2c, 9);
    LOAD3(B3a,X3a,Y3a,10);  LOAD3(B3b,X3b,Y3b,11);  LOAD3(B3c,X3c,Y3c,12);

    int t = 1;
    for (; t + 12 <= Teff; t += 12){
        WAITV(27); SB0();                      // bank0's 9 loads done
        stepf(B0a,X0a,Y0a); stepf(B0b,X0b,Y0b); stepf(B0c,X0c,Y0c);
        LOAD3(B0a,X0a,Y0a, t+12); LOAD3(B0b,X0b,Y0b, t+13); LOAD3(B0c,X0c,Y0c, t+14);

        WAITV(27); SB0();                      // bank1 done
        stepf(B1a,X1a,Y1a); stepf(B1b,X1b,Y1b); stepf(B1c,X1c,Y1c);
        RESCALE4(a0, a1, a2, a3, E);
        LOAD3(B1a,X1a,Y1a, t+15); LOAD3(B1b,X1b,Y1b, t+16); LOAD3(B1c,X1c,Y1c, t+17);

        WAITV(27); SB0();                      // bank2 done
        stepf(B2a,X2a,Y2a); stepf(B2b,X2b,Y2b); stepf(B2c,X2c,Y2c);
        LOAD3(B2a,X2a,Y2a, t+18); LOAD3(B2b,X2b,Y2b, t+19); LOAD3(B2c,X2c,Y2c, t+20);

        WAITV(27); SB0();                      // bank3 done
        stepf(B3a,X3a,Y3a); stepf(B3b,X3b,Y3b); stepf(B3c,X3c,Y3c);
        RESCALE4(a0, a1, a2, a3, E);
        LOAD3(B3a,X3a,Y3a, t+21); LOAD3(B3b,X3b,Y3b, t+22); LOAD3(B3c,X3c,Y3c, t+23);
    }

    // tail (<12 steps): banks hold rows t..t+11
    WAITV(0); SB0();
    if (t + 0 < Teff) stepf(B0a,X0a,Y0a);
    if (t + 1 < Teff) stepf(B0b,X0b,Y0b);
    if (t + 2 < Teff) stepf(B0c,X0c,Y0c);
    if (t + 0 < Teff) RESCALE4(a0, a1, a2, a3, E);
    if (t + 3 < Teff) stepf(B1a,X1a,Y1a);
    if (t + 4 < Teff) stepf(B1b,X1b,Y1b);
    if (t + 5 < Teff) stepf(B1c,X1c,Y1c);
    if (t + 3 < Teff) RESCALE4(a0, a1, a2, a3, E);
    if (t + 6 < Teff) stepf(B2a,X2a,Y2a);
    if (t + 7 < Teff) stepf(B2b,X2b,Y2b);
    if (t + 8 < Teff) stepf(B2c,X2c,Y2c);
    if (t + 6 < Teff) RESCALE4(a0, a1, a2, a3, E);
    if (t + 9 < Teff) stepf(B3a,X3a,Y3a);
    if (t +10 < Teff) stepf(B3b,X3b,Y3b);
    if (t +11 < Teff) stepf(B3c,X3c,Y3c);

#undef LOAD3

    __shared__ __align__(16) float aout[256];
    reinterpret_cast<float4*>(aout)[lane] = make_float4(a0, a1, a2, a3);
    __syncthreads();
    if (lane == 0){
        float hi = aout[2*ll], lo = aout[2*ll - 1];
        loss[sq * N + n] = -(flog2(hi + lo) + (float)E) * LN2F;
    }
}

__global__ __launch_bounds__(256) void ctc_finalize_kernel(
    const float* __restrict__ ws, float* __restrict__ out, int N)
{
    __shared__ float sc[256], sh[256];
    const int i = threadIdx.x;
    float c = 0.f, h = 0.f;
    for (int nn = i; nn < N; nn += 256) {
        float cv = ws[nn];
        float rv = ws[N + nn];
        c += cv;
        float dap = fabsf(1e-6f - cv);
        float dan = fabsf(1e-6f - rv);
        h += fmaxf(dap - dan + 16.0f, 0.f);
    }
    sc[i] = c; sh[i] = h;
    __syncthreads();
    for (int off = 128; off > 0; off >>= 1) {
        if (i < off) { sc[i] += sc[i + off]; sh[i] += sh[i + off]; }
        __syncthreads();
    }
    if (i == 0) out[0] = sc[0] + sh[0] / (float)N;
}

extern "C" void kernel_launch(void* const* d_in, const int* in_sizes, int n_in,
                              void* d_out, int out_size, void* d_ws, size_t ws_size,
                              hipStream_t stream) {
    const float* lp      = (const float*)d_in[0];   // predicts (T,N,C) f32
    const int* labels    = (const int*)d_in[1];     // (N,S)
    const int* rlabels   = (const int*)d_in[2];     // (N,S)
    const int* plen      = (const int*)d_in[3];     // (N,)
    const int* llen      = (const int*)d_in[4];     // (N,)
    const int* rlen      = (const int*)d_in[5];     // (N,)

    const int N = in_sizes[3];
    const int S = in_sizes[1] / N;
    const int C = 256;
    const int T = in_sizes[0] / (N * C);

    float* ws = (float*)d_ws;                       // 2N floats of per-seq losses

    ctc_scan_kernel<<<2 * N, 64, 0, stream>>>(lp, labels, rlabels, plen, llen, rlen,
                                              ws, T, N, C, S);
    ctc_finalize_kernel<<<1, 256, 0, stream>>>(ws, (float*)d_out, N);
}